// Round 6
// baseline (69.403 us; speedup 1.0000x reference)
//
#include <hip/hip_runtime.h>

#define NSCALES 20
#define PATCH 100
#define IMGS_PER_SCALE 1600
#define TOTAL_IMGS 32000
#define THREADS 256
#define CHUNKPX 2048                    // pixels per chunk (>= 41*41=1681)
#define NF4CHUNK 1536                   // float4 per chunk
#define NBLK 2560                       // persistent-ish grid
#define SLOTS 4                         // cntL slot spread (cuts atomic serial)
#define CNTSZ 1024                      // 229 imgs * 4 slots, padded
#define S2MAX 1681

struct Ptrs   { const float* p[NSCALES]; };
struct Starts { int chunkStart[NSCALES]; int nchunks; };

// ---------------------------------------------------------------------------
// issue 6 float4 loads for a chunk (4px/thread x 2 groups, 48B lane stride)
// ---------------------------------------------------------------------------
__device__ __forceinline__ void issue_loads(const float4* __restrict__ x4,
                                            int FC, int NF4tot, int tid,
                                            float4* v)
{
    #pragma unroll
    for (int i = 0; i < 3; i++) v[i]     = x4[min(FC + tid * 3 + i, NF4tot - 1)];
    #pragma unroll
    for (int i = 0; i < 3; i++) v[3 + i] = x4[min(FC + 768 + tid * 3 + i, NF4tot - 1)];
}

// ---------------------------------------------------------------------------
// compute one chunk from registers (templated on S; all divides constant)
// ---------------------------------------------------------------------------
template<int S>
__device__ __forceinline__ void compute_chunk(const float* __restrict__ x,
                                              int chunkLocal, const float4* v,
                                              int tid, int* cntL)
{
    constexpr int S2 = S * S;
    constexpr int ROWDIV = 100 * S;
    const int Ntot = IMGS_PER_SCALE * S2;
    const int P0   = chunkLocal * CHUNKPX;
    const int Pend = min(P0 + CHUNKPX, Ntot);
    const int imgBase = P0 / S2;
    const int slot = tid & (SLOTS - 1);

    #pragma unroll
    for (int g = 0; g < 2; g++) {
        const int p0 = P0 + g * (CHUNKPX / 2) + tid * 4;
        if (p0 < Pend) {                          // multiples of 4: p0+3 ok
            const float4 A = v[3 * g], B = v[3 * g + 1], C = v[3 * g + 2];
            const int iA = p0 / S2;               // constant-divisor magic
            const int r0 = p0 - iA * S2;
            const int jA = p0 / ROWDIV;
            const int jB = (p0 + 3) / ROWDIV;
            const float* ceA = x + (size_t)(((jA * PATCH + 49) * S + (S >> 1)) * 3);
            float a0 = ceA[0], a1 = ceA[1], a2 = ceA[2];   // broadcast loads
            float b0 = a0, b1 = a1, b2 = a2;
            int flip = 4;
            if (jB != jA) {
                const float* ceB = x + (size_t)(((jB * PATCH + 49) * S + (S >> 1)) * 3);
                b0 = ceB[0]; b1 = ceB[1]; b2 = ceB[2];
                flip = (jA + 1) * ROWDIV - p0;
            }
            int cA = 0, cB = 0;
            #pragma unroll
            for (int q = 0; q < 4; q++) {         // compile-time component sel
                float f0 = (q==0)?A.x:(q==1)?A.w:(q==2)?B.z:C.y;
                float f1 = (q==0)?A.y:(q==1)?B.x:(q==2)?B.w:C.z;
                float f2 = (q==0)?A.z:(q==1)?B.y:(q==2)?C.x:C.w;
                float e0 = (q < flip) ? a0 : b0;
                float e1 = (q < flip) ? a1 : b1;
                float e2 = (q < flip) ? a2 : b2;
                float d = fmaxf(fmaxf(fabsf(f0 - e0), fabsf(f1 - e1)),
                                fabsf(f2 - e2));
                int fg = (d <= (float)S) ? 1 : 0;
                int t  = r0 + q;                  // 4px spans <= 2 images
                cA += (t < S2) ? fg : 0;
                cB += (t >= S2) ? fg : 0;
            }
            atomicAdd(&cntL[(iA - imgBase) * SLOTS + slot], cA);
            if (cB) atomicAdd(&cntL[(iA + 1 - imgBase) * SLOTS + slot], cB);
        }
    }
}

// ---------------------------------------------------------------------------
// flush chunk counts -> two deterministic global slots per image
// ---------------------------------------------------------------------------
template<int S>
__device__ __forceinline__ void flush_chunk(int chunkLocal, int sc,
                                            const int* cntL,
                                            int* __restrict__ wsC2, int tid)
{
    constexpr int S2 = S * S;
    const int Ntot = IMGS_PER_SCALE * S2;
    const int P0   = chunkLocal * CHUNKPX;
    const int Pend = min(P0 + CHUNKPX, Ntot);
    const int imgBase = P0 / S2;
    const int imgLast = (Pend - 1) / S2;
    const int nImg = imgLast - imgBase + 1;       // <= 229
    for (int t = tid; t < nImg; t += THREADS) {
        int img = imgBase + t;
        int lo = img * S2, hi = lo + S2;
        int v = cntL[t * SLOTS] + cntL[t * SLOTS + 1]
              + cntL[t * SLOTS + 2] + cntL[t * SLOTS + 3];
        int g = sc * IMGS_PER_SCALE + img;
        if (lo >= P0) {                           // I own the image start
            wsC2[2 * g] = v;
            if (hi <= Pend) wsC2[2 * g + 1] = 0;  // fully mine
        } else {
            wsC2[2 * g + 1] = v;                  // continuation
        }
    }
}

// ---------------------------------------------------------------------------
// Kernel 1: persistent grid-stride over chunks, register double-buffered.
// ---------------------------------------------------------------------------
__global__ __launch_bounds__(THREADS)
void count_kernel(Ptrs ptrs, Starts st, int* __restrict__ wsC2)
{
    __shared__ int cntL[CNTSZ];
    const int tid = threadIdx.x;
    float4 vA[6], vB[6];

    int c = blockIdx.x;                           // NBLK <= nchunks
    int sc = 0;
    #pragma unroll
    for (int k = 1; k < NSCALES; k++) sc += (c >= st.chunkStart[k]) ? 1 : 0;
    {
        int cl = c - st.chunkStart[sc];
        int s = 3 + 2 * sc;
        int NF4 = IMGS_PER_SCALE * s * s * 3 / 4;
        issue_loads((const float4*)ptrs.p[sc], cl * NF4CHUNK, NF4, tid, vA);
    }
    for (int t = tid; t < CNTSZ; t += THREADS) cntL[t] = 0;
    __syncthreads();

    for (;;) {
        // prefetch next chunk while computing current
        const int cn = c + NBLK;
        int scn = 0;
        if (cn < st.nchunks) {
            #pragma unroll
            for (int k = 1; k < NSCALES; k++) scn += (cn >= st.chunkStart[k]) ? 1 : 0;
            int cln = cn - st.chunkStart[scn];
            int s = 3 + 2 * scn;
            int NF4 = IMGS_PER_SCALE * s * s * 3 / 4;
            issue_loads((const float4*)ptrs.p[scn], cln * NF4CHUNK, NF4, tid, vB);
        }

        const int cl = c - st.chunkStart[sc];
        switch (sc) {
#define CASE(i) case i: \
            compute_chunk<3 + 2*(i)>(ptrs.p[i], cl, vA, tid, cntL); \
            __syncthreads(); \
            flush_chunk<3 + 2*(i)>(cl, i, cntL, wsC2, tid); break;
            CASE(0)  CASE(1)  CASE(2)  CASE(3)  CASE(4)
            CASE(5)  CASE(6)  CASE(7)  CASE(8)  CASE(9)
            CASE(10) CASE(11) CASE(12) CASE(13) CASE(14)
            CASE(15) CASE(16) CASE(17) CASE(18) CASE(19)
#undef CASE
        }
        __syncthreads();                          // flush reads done
        for (int t = tid; t < CNTSZ; t += THREADS) cntL[t] = 0;
        if (cn >= st.nchunks) break;
        __syncthreads();                          // zero visible
        #pragma unroll
        for (int i = 0; i < 6; i++) vA[i] = vB[i];
        c = cn; sc = scn;
    }
}

// ---------------------------------------------------------------------------
// Kernel 2: classify + CC for partial images. 500 blocks x 64 images.
// ---------------------------------------------------------------------------
__global__ __launch_bounds__(THREADS)
void cc_kernel(Ptrs ptrs, const int* __restrict__ wsC2,
               int* __restrict__ wsCnt,
               int* __restrict__ wsNcomp, int* __restrict__ wsMaxc)
{
    const int bid = blockIdx.x;                 // 25 blocks per scale
    const int sc  = bid / 25;
    const int s   = 3 + 2 * sc;
    const int s2  = s * s;
    const int BIGL = s2 + 1;
    const float* __restrict__ x = ptrs.p[sc];
    const int imgLoc0 = (bid % 25) * 64;
    const int tid = threadIdx.x;
    const unsigned mS = 0xFFFFFFFFu / (unsigned)s + 1;

    __shared__ int slowList[64];
    __shared__ int nslow;
    __shared__ int lab[S2MAX];
    __shared__ int szh[S2MAX];
    __shared__ int redN[4], redM[4];

    if (tid == 0) nslow = 0;
    __syncthreads();
    if (tid < 64) {
        int img = imgLoc0 + tid;
        int g = sc * IMGS_PER_SCALE + img;
        int c = wsC2[2 * g] + wsC2[2 * g + 1];
        wsCnt[g] = c;
        if (c == s2)      { wsNcomp[g] = 1; wsMaxc[g] = s2; }
        else if (c == 0)  { wsNcomp[g] = 0; wsMaxc[g] = 0; }
        else { int k = atomicAdd(&nslow, 1); slowList[k] = img; }
    }
    __syncthreads();
    const int ns = nslow;
    if (ns == 0) return;

    if (s2 <= 64) {
        // ---- per-wave shuffle CC, one image per wave iteration ----
        const int w = tid >> 6, l = tid & 63;
        for (int idx = w; idx < ns; idx += 4) {
            int img = slowList[idx];
            int fg = 0, labr = BIGL, i1 = 0, i2 = 0;
            if (l < s2) {
                i1 = (int)__umulhi((unsigned)l, mS);
                i2 = l - i1 * s;
                int M = img * s + i1;
                int j = M / PATCH;
                const float* ce = x + (size_t)(((j * PATCH + 49) * s + (s >> 1)) * 3);
                const float* px = x + ((size_t)img * s2 + l) * 3;
                float d = fmaxf(fmaxf(fabsf(px[0] - ce[0]), fabsf(px[1] - ce[1])),
                                fabsf(px[2] - ce[2]));
                if (d <= (float)s) { fg = 1; labr = l + 1; }
            }
            for (;;) {
                int m = labr;
                int vU = __shfl(labr, (l - s) & 63);
                int vD = __shfl(labr, (l + s) & 63);
                int vL = __shfl(labr, (l - 1) & 63);
                int vR = __shfl(labr, (l + 1) & 63);
                if (fg) {
                    if (i1 > 0)     m = min(m, vU);
                    if (i1 < s - 1) m = min(m, vD);
                    if (i2 > 0)     m = min(m, vL);
                    if (i2 < s - 1) m = min(m, vR);
                }
                int vJ = __shfl(labr, (m - 1) & 63);      // pointer jump
                if (fg) m = min(m, vJ);
                unsigned long long chg = __ballot(m < labr);
                labr = m;
                if (chg == 0) break;
            }
            int ncomp = __popcll(__ballot(fg && labr == l + 1));
            int mc = 0;
            for (int r = 0; r < s2; r++) {
                int szr = __popcll(__ballot(fg && labr == r + 1));
                mc = max(mc, szr);
            }
            if (l == 0) {
                int g = sc * IMGS_PER_SCALE + img;
                wsNcomp[g] = ncomp; wsMaxc[g] = mc;
            }
        }
    } else {
        // ---- block-sequential LDS CC (bg pixel at s>=9: vanishingly rare) --
        for (int idx = 0; idx < ns; idx++) {
            int img = slowList[idx];
            const int ibase = img * s2 * 3;
            for (int i = tid; i < s2; i += THREADS) {
                int i1 = (int)__umulhi((unsigned)i, mS);
                int M = img * s + i1;
                int j = M / PATCH;
                const float* ce = x + (size_t)(((j * PATCH + 49) * s + (s >> 1)) * 3);
                const float* px = x + ibase + i * 3;
                float d = fmaxf(fmaxf(fabsf(px[0] - ce[0]), fabsf(px[1] - ce[1])),
                                fabsf(px[2] - ce[2]));
                lab[i] = (d <= (float)s) ? (i + 1) : BIGL;
                szh[i] = 0;
            }
            __syncthreads();
            for (;;) {
                bool changed = false;
                for (int i = tid; i < s2; i += THREADS) {
                    int L0 = lab[i];
                    if (L0 <= s2) {
                        int i1 = (int)__umulhi((unsigned)i, mS);
                        int i2 = i - i1 * s;
                        int m = L0;
                        if (i1 > 0)     m = min(m, lab[i - s]);
                        if (i1 < s - 1) m = min(m, lab[i + s]);
                        if (i2 > 0)     m = min(m, lab[i - 1]);
                        if (i2 < s - 1) m = min(m, lab[i + 1]);
                        m = min(m, lab[m - 1]);
                        if (m < L0) { lab[i] = m; changed = true; }
                    }
                }
                if (__syncthreads_count(changed ? 1 : 0) == 0) break;
            }
            int ncomp = 0;
            for (int i = tid; i < s2; i += THREADS) {
                int L = lab[i];
                if (L <= s2) {
                    atomicAdd(&szh[L - 1], 1);
                    if (L == i + 1) ncomp++;
                }
            }
            __syncthreads();
            int mc = 0;
            for (int i = tid; i < s2; i += THREADS) mc = max(mc, szh[i]);
            for (int m = 32; m >= 1; m >>= 1) {
                ncomp += __shfl_xor(ncomp, m);
                mc     = max(mc, __shfl_xor(mc, m));
            }
            int wid = tid >> 6, lane = tid & 63;
            if (lane == 0) { redN[wid] = ncomp; redM[wid] = mc; }
            __syncthreads();
            if (tid == 0) {
                int g = sc * IMGS_PER_SCALE + img;
                wsNcomp[g] = redN[0] + redN[1] + redN[2] + redN[3];
                wsMaxc[g]  = max(max(redM[0], redM[1]), max(redM[2], redM[3]));
            }
            __syncthreads();
        }
    }
}

// ---------------------------------------------------------------------------
// Kernel 3: per-scale finalization (verified).
// ---------------------------------------------------------------------------
__global__ __launch_bounds__(THREADS)
void final_kernel(const int* __restrict__ wsCnt,
                  const int* __restrict__ wsNcomp,
                  const int* __restrict__ wsMaxc,
                  float* __restrict__ out)
{
    const int scale = blockIdx.x;
    const int s  = 3 + 2 * scale;
    const int s2 = s * s;
    const int tid = threadIdx.x;
    const int NB = IMGS_PER_SCALE;
    const int CH = 7;

    __shared__ int nc[IMGS_PER_SCALE];
    __shared__ int tsum[THREADS];

    for (int i = tid; i < NB; i += THREADS) nc[i] = wsNcomp[scale * NB + i];
    __syncthreads();

    int lsum = 0;
    for (int k = 0; k < CH; k++) {
        int idx = tid * CH + k;
        if (idx < NB) lsum += nc[idx];
    }
    tsum[tid] = lsum;
    __syncthreads();
    for (int st = 1; st < THREADS; st <<= 1) {
        int v = (tid >= st) ? tsum[tid - st] : 0;
        __syncthreads();
        tsum[tid] += v;
        __syncthreads();
    }
    int run = (tid > 0) ? tsum[tid - 1] : 0;
    for (int k = 0; k < CH; k++) {
        int idx = tid * CH + k;
        if (idx < NB) {
            int v = nc[idx];
            run += v;
            nc[idx] = (v > 0) ? run : 0;
        }
    }
    __syncthreads();

    int b    = tid >> 4;
    int lane = tid & 15;
    float fdsum = 0.f, sn = 0.f, sn2 = 0.f, pcsum = 0.f;
    int pqc = 0, bg = 0, mcx = 0;
    for (int q = lane; q < PATCH; q += 16) {
        int i = b * PATCH + q;
        int c = wsCnt[scale * NB + i];
        float n = (c > 0) ? (float)c : 1.0f;
        fdsum += 1.0f / n;
        sn    += n;
        sn2   += n * n;
        pqc   += ((float)c / (float)s2 >= 0.59275f) ? 1 : 0;
        bg    += (s2 - c);
        mcx    = max(mcx, wsMaxc[scale * NB + i]);
        pcsum += (float)nc[i];
    }
    for (int m = 8; m >= 1; m >>= 1) {
        fdsum += __shfl_xor(fdsum, m);
        sn    += __shfl_xor(sn, m);
        sn2   += __shfl_xor(sn2, m);
        pcsum += __shfl_xor(pcsum, m);
        pqc   += __shfl_xor(pqc, m);
        bg    += __shfl_xor(bg, m);
        mcx    = max(mcx, __shfl_xor(mcx, m));
    }
    if (lane == 0) {
        float fd  = fdsum / 100.0f;
        float m1  = sn / 100.0f;
        float mu1 = m1 * m1;
        float mu2 = sn2 / 100.0f;
        float lac = (mu2 - mu1) / mu1;
        float pq  = (float)pqc / 100.0f;
        float pc  = pcsum / 100.0f;
        float pm  = (float)max(bg, mcx);
        out[b * 100 +  0 + scale] = pc;
        out[b * 100 + 20 + scale] = pq;
        out[b * 100 + 40 + scale] = pm;
        out[b * 100 + 60 + scale] = lac;
        out[b * 100 + 80 + scale] = fd;
    }
}

extern "C" void kernel_launch(void* const* d_in, const int* in_sizes, int n_in,
                              void* d_out, int out_size, void* d_ws, size_t ws_size,
                              hipStream_t stream)
{
    Ptrs ptrs;
    for (int i = 0; i < NSCALES; i++) ptrs.p[i] = (const float*)d_in[i];

    Starts st;
    int acc = 0;
    for (int i = 0; i < NSCALES; i++) {
        st.chunkStart[i] = acc;
        int s = 3 + 2 * i, s2 = s * s;
        acc += (IMGS_PER_SCALE * s2 + CHUNKPX - 1) / CHUNKPX;
    }
    st.nchunks = acc;                            // 9641

    int* wsC2  = (int*)d_ws;                    // 2 slots per image
    int* wsCnt = wsC2 + 2 * TOTAL_IMGS;
    int* wsN   = wsCnt + TOTAL_IMGS;
    int* wsM   = wsN + TOTAL_IMGS;

    count_kernel<<<NBLK, THREADS, 0, stream>>>(ptrs, st, wsC2);
    cc_kernel<<<TOTAL_IMGS / 64, THREADS, 0, stream>>>(ptrs, wsC2, wsCnt, wsN, wsM);
    final_kernel<<<NSCALES, THREADS, 0, stream>>>(wsCnt, wsN, wsM, (float*)d_out);
}